// Round 7
// baseline (247.043 us; speedup 1.0000x reference)
//
#include <hip/hip_runtime.h>

#define CIN 128
#define COUT 128
#define NB_MAX 512          // max buckets (N<=131072 at 256 nodes/bucket)
#define BCAP 10240          // records per bucket; E[bucket]=8192, sd~91 -> 22-sigma margin
#define EPB 8192            // edges per partition block (256 thr x 32)
#define SB 16               // src bins per node (coarse src sort for L2 locality)
#define NBINS (256 * SB)    // 4096 combined (dst_local, src_bin) keys

typedef float f32x4 __attribute__((ext_vector_type(4)));   // native vec for nontemporal builtin

__device__ __forceinline__ unsigned short f2bf(float x) {
    unsigned int b = __float_as_uint(x);
    b += 0x7FFFu + ((b >> 16) & 1u);           // round-to-nearest-even
    return (unsigned short)(b >> 16);
}
__device__ __forceinline__ float bf2f_hi(unsigned int u) {      // high half of dword
    return __uint_as_float(u & 0xFFFF0000u);
}
__device__ __forceinline__ float bf2f_lo(unsigned int u) {      // low half of dword
    return __uint_as_float(u << 16);
}

// ---------------- zero bucket cursors ----------------
__global__ void k_zero(int* __restrict__ cursor, int NB) {
    int i = blockIdx.x * blockDim.x + threadIdx.x;
    if (i < NB) cursor[i] = 0;
}

// ---------------- LDS-staged radix partition by dst>>8 ----------------
__global__ __launch_bounds__(256) void k_part(const int* __restrict__ ei, const float* __restrict__ ew,
                                              int* __restrict__ cursor,
                                              unsigned long long* __restrict__ brec,
                                              int E, int NB) {
    __shared__ int hist[NB_MAX];
    __shared__ int base_[NB_MAX];
    int t = threadIdx.x;
    int chunk0 = blockIdx.x * EPB;

    for (int i = t; i < NB; i += 256) hist[i] = 0;
    __syncthreads();

    #pragma unroll 4
    for (int k = 0; k < EPB / 256; ++k) {
        int e = chunk0 + k * 256 + t;
        if (e < E) atomicAdd(&hist[ei[E + e] >> 8], 1);
    }
    __syncthreads();

    for (int i = t; i < NB; i += 256) {
        int c = hist[i];
        base_[i] = (c > 0) ? atomicAdd(&cursor[i], c) : 0;
        hist[i] = 0;                       // reuse as local cursor
    }
    __syncthreads();

    #pragma unroll 4
    for (int k = 0; k < EPB / 256; ++k) {
        int e = chunk0 + k * 256 + t;
        if (e < E) {
            int s = ei[e];
            int d = ei[E + e];
            int b = d >> 8;
            unsigned int q = (unsigned int)(ew[e] * 32767.0f + 0.5f);
            unsigned int low = ((unsigned int)s << 15) | q;
            int lp = atomicAdd(&hist[b], 1);
            int pos = base_[b] + lp;
            if (pos < BCAP)
                brec[(size_t)b * BCAP + pos] =
                    ((unsigned long long)(d & 255) << 32) | low;
        }
    }
}

// ---------------- per-bucket LDS sort by (dst_local, src_bin) -> exact CSR + dis ----------------
// Sorting each node's edge list into ascending coarse-src order makes the
// aggregation's gathers sweep h' as a chip-wide moving window (L2-resident).
__global__ __launch_bounds__(256) void k_sortdeg(const unsigned long long* __restrict__ brec,
                                                 const int* __restrict__ cursor,
                                                 unsigned int* __restrict__ srec,
                                                 int2* __restrict__ rowinfo,
                                                 float* __restrict__ dis, int N, int srcshift) {
    __shared__ int bins[NBINS];            // 16 KB: histogram, then per-bin cursors
    __shared__ int scanB[256];
    __shared__ int degq[256];
    __shared__ unsigned int stage[BCAP];   // 40 KB
    int t = threadIdx.x;
    int b = blockIdx.x;
    int cnt = min(cursor[b], BCAP);
    const unsigned long long* r = brec + (size_t)b * BCAP;

    for (int i = t; i < NBINS; i += 256) bins[i] = 0;
    degq[t] = 0;
    __syncthreads();

    // pass 1: histogram by (dst_local, src_bin) + integer-exact weighted degree
    for (int j = t; j < cnt; j += 256) {
        unsigned long long v = r[j];
        int dl = (int)(v >> 32);
        unsigned int low = (unsigned int)v;
        int key = dl * SB + (int)((low >> 15) >> srcshift);
        atomicAdd(&bins[key], 1);
        atomicAdd(&degq[dl], (int)(low & 0x7FFFu));
    }
    __syncthreads();

    // per-node count (sum of its 16 bins), block scan, then intra-node bin prefix
    int base = t * SB;
    int c = 0;
    #pragma unroll
    for (int k = 0; k < SB; ++k) c += bins[base + k];
    scanB[t] = c;
    __syncthreads();
    #pragma unroll
    for (int off = 1; off < 256; off <<= 1) {
        int v = (t >= off) ? scanB[t - off] : 0;
        __syncthreads();
        scanB[t] += v;
        __syncthreads();
    }
    int excl = scanB[t] - c;
    int run = excl;
    #pragma unroll
    for (int k = 0; k < SB; ++k) { int v = bins[base + k]; bins[base + k] = run; run += v; }

    int n = b * 256 + t;
    if (n < N) {
        dis[n] = rsqrtf(1.0f + (float)degq[t] * (1.0f / 32767.0f));
        rowinfo[n] = make_int2(b * BCAP + excl, c);
    }
    __syncthreads();

    // pass 2: scatter into LDS stage, grouped by (node, ascending src bin)
    for (int j = t; j < cnt; j += 256) {
        unsigned long long v = r[j];
        int dl = (int)(v >> 32);
        unsigned int low = (unsigned int)v;
        int key = dl * SB + (int)((low >> 15) >> srcshift);
        int pos = atomicAdd(&bins[key], 1);
        stage[pos] = low;
    }
    __syncthreads();

    unsigned int* so = srec + (size_t)b * BCAP;
    for (int j = t; j < cnt; j += 256) so[j] = stage[j];
}

// ---------------- GEMM: h'[n] = bf16( (X[n] @ W) * dis[n] ) ----------------
// 128x128 block tile, 8x8 per thread (as 4x4 split across 64-offset), K-block 16.
#define GK 16
#define LDP 132    // padded LDS row (floats): 16B-aligned rows, conflict-free inner reads
__global__ __launch_bounds__(256) void k_gemm(const float* __restrict__ X, const float* __restrict__ W,
                                              const float* __restrict__ dis,
                                              unsigned short* __restrict__ h, int N) {
    __shared__ float Xs[GK][LDP];   // k-major: Xs[k][node]
    __shared__ float Ws[GK][LDP];   // Ws[k][col]
    int t = threadIdx.x;
    int tx = t & 15;                // col split-tile: cols {tx*4+q, 64+tx*4+q}
    int ty = t >> 4;                // node split-tile: nodes {ty*4+i, 64+ty*4+i}
    int n0 = blockIdx.x * 128;

    float acc[8][8] = {};           // [node 0..3,64..67][col 0..3,64..67]

    for (int ko = 0; ko < CIN; ko += GK) {
        __syncthreads();
        // stage X (128 nodes x GK k), transposed into Xs[k][node]
        #pragma unroll
        for (int i = 0; i < 2; ++i) {
            int idx = t + i * 256;          // 0..511 float4s
            int node = idx >> 2;            // 4 float4 per node
            int kq = idx & 3;
            float4 v = make_float4(0.f, 0.f, 0.f, 0.f);
            if (n0 + node < N) v = *(const float4*)(X + (size_t)(n0 + node) * CIN + ko + kq * 4);
            Xs[kq * 4 + 0][node] = v.x;
            Xs[kq * 4 + 1][node] = v.y;
            Xs[kq * 4 + 2][node] = v.z;
            Xs[kq * 4 + 3][node] = v.w;
        }
        // stage W (GK rows x 128 cols)
        #pragma unroll
        for (int i = 0; i < 2; ++i) {
            int idx = t + i * 256;          // 0..511 float4s
            int kr = idx >> 5;              // 32 float4 per k-row
            int cq = idx & 31;
            float4 v = *(const float4*)(W + (size_t)(ko + kr) * COUT + cq * 4);
            *(float4*)(&Ws[kr][cq * 4]) = v;
        }
        __syncthreads();

        #pragma unroll
        for (int kk = 0; kk < GK; ++kk) {
            float x[8], w[8];
            *(float4*)&x[0] = *(const float4*)&Xs[kk][ty * 4];
            *(float4*)&x[4] = *(const float4*)&Xs[kk][64 + ty * 4];
            *(float4*)&w[0] = *(const float4*)&Ws[kk][tx * 4];
            *(float4*)&w[4] = *(const float4*)&Ws[kk][64 + tx * 4];
            #pragma unroll
            for (int i = 0; i < 8; ++i)
                #pragma unroll
                for (int q = 0; q < 8; ++q)
                    acc[i][q] += x[i] * w[q];
        }
    }

    // epilogue: scale by dis, pack bf16, store 8B per half-row
    #pragma unroll
    for (int i = 0; i < 8; ++i) {
        int node = n0 + ((i < 4) ? (ty * 4 + i) : (64 + ty * 4 + (i - 4)));
        if (node < N) {
            float dn = dis[node];
            uint2 p0, p1;
            p0.x = (unsigned int)f2bf(acc[i][0] * dn) | ((unsigned int)f2bf(acc[i][1] * dn) << 16);
            p0.y = (unsigned int)f2bf(acc[i][2] * dn) | ((unsigned int)f2bf(acc[i][3] * dn) << 16);
            p1.x = (unsigned int)f2bf(acc[i][4] * dn) | ((unsigned int)f2bf(acc[i][5] * dn) << 16);
            p1.y = (unsigned int)f2bf(acc[i][6] * dn) | ((unsigned int)f2bf(acc[i][7] * dn) << 16);
            *(uint2*)(h + (size_t)node * COUT + tx * 4)      = p0;
            *(uint2*)(h + (size_t)node * COUT + 64 + tx * 4) = p1;
        }
    }
}

// ---------------- aggregation: out[n] = dis[n]*(h'[n] + sum ew*h'[src]) + b ----------------
// 2 nodes per wave; 16 lanes per edge (uint4 = 8 bf16 channels per lane);
// one gather instr covers 4 edges; srec records prefetched one batch ahead.
// Edge lists arrive src-sorted (coarse) -> gathers sweep h' as a moving window.
__global__ __launch_bounds__(256) void k_agg(const unsigned short* __restrict__ h,
                                             const unsigned int* __restrict__ srec,
                                             const int2* __restrict__ rowinfo,
                                             const float* __restrict__ dis,
                                             const float* __restrict__ bias,
                                             float* __restrict__ out, int N) {
    int wave = threadIdx.x >> 6;
    int lane = threadIdx.x & 63;
    int slot = lane >> 4;            // 0..3: {nodeA,e0},{nodeA,e1},{nodeB,e0},{nodeB,e1}
    int sl   = slot & 1;             // edge parity within node
    int cl   = lane & 15;            // 16B group within row (8 bf16 channels)
    int node = blockIdx.x * 8 + wave * 2 + (slot >> 1);
    bool valid = node < N;
    int2 ri = valid ? rowinfo[node] : make_int2(0, 0);
    const unsigned int* r = srec + ri.x;
    int m = ri.y;
    const uint4* hu = (const uint4*)h;   // 16 uint4 per 128-channel row

    float a[8] = {0.f, 0.f, 0.f, 0.f, 0.f, 0.f, 0.f, 0.f};
    if (valid && sl == 0) {              // self-loop term (h' already carries dis[n])
        uint4 us = hu[(size_t)node * 16 + cl];
        a[0] = bf2f_lo(us.x); a[1] = bf2f_hi(us.x);
        a[2] = bf2f_lo(us.y); a[3] = bf2f_hi(us.y);
        a[4] = bf2f_lo(us.z); a[5] = bf2f_hi(us.z);
        a[6] = bf2f_lo(us.w); a[7] = bf2f_hi(us.w);
    }

    unsigned int rrc[4];
    #pragma unroll
    for (int u = 0; u < 4; ++u) {
        int j = u * 2 + sl;
        rrc[u] = (j < m) ? r[j] : 0u;
    }
    for (int j0 = 0; j0 < m; j0 += 8) {
        unsigned int rrn[4];
        #pragma unroll
        for (int u = 0; u < 4; ++u) {        // prefetch next batch's records
            int j = j0 + 8 + u * 2 + sl;
            rrn[u] = (j < m) ? r[j] : 0u;
        }
        #pragma unroll
        for (int u = 0; u < 4; ++u) {        // gather + accumulate current batch
            unsigned int rr = rrc[u];
            float w = (float)(rr & 0x7FFFu) * (1.0f / 32767.0f);
            uint4 v = hu[(size_t)(rr >> 15) * 16 + cl];
            a[0] += w * bf2f_lo(v.x); a[1] += w * bf2f_hi(v.x);
            a[2] += w * bf2f_lo(v.y); a[3] += w * bf2f_hi(v.y);
            a[4] += w * bf2f_lo(v.z); a[5] += w * bf2f_hi(v.z);
            a[6] += w * bf2f_lo(v.w); a[7] += w * bf2f_hi(v.w);
        }
        #pragma unroll
        for (int u = 0; u < 4; ++u) rrc[u] = rrn[u];
    }

    #pragma unroll
    for (int i = 0; i < 8; ++i) a[i] += __shfl_xor(a[i], 16);   // combine edge-parity pair

    if (valid && sl == 0) {
        float dn = dis[node];
        float4 b0 = *(const float4*)(bias + cl * 8);
        float4 b1 = *(const float4*)(bias + cl * 8 + 4);
        f32x4 o0 = {a[0] * dn + b0.x, a[1] * dn + b0.y, a[2] * dn + b0.z, a[3] * dn + b0.w};
        f32x4 o1 = {a[4] * dn + b1.x, a[5] * dn + b1.y, a[6] * dn + b1.z, a[7] * dn + b1.w};
        f32x4* op = (f32x4*)(out + (size_t)node * COUT + cl * 8);
        __builtin_nontemporal_store(o0, op);        // write-once: keep out of L2
        __builtin_nontemporal_store(o1, op + 1);
    }
}

// ---------------- launch ----------------
extern "C" void kernel_launch(void* const* d_in, const int* in_sizes, int n_in,
                              void* d_out, int out_size, void* d_ws, size_t ws_size,
                              hipStream_t stream) {
    const float* X    = (const float*)d_in[0];
    const int*   ei   = (const int*)d_in[1];
    const float* ew   = (const float*)d_in[2];
    const float* W    = (const float*)d_in[3];
    const float* bias = (const float*)d_in[4];
    float* out = (float*)d_out;

    int E = in_sizes[2];            // edge_weight count
    int N = out_size / COUT;        // B == 1
    int NB = (N + 255) >> 8;        // buckets of 256 nodes

    int srcshift = 0;               // smallest shift with (N-1)>>shift < SB
    while (((N - 1) >> srcshift) >= SB) ++srcshift;

    // workspace carve-up (~75 MB)
    char* ws = (char*)d_ws;
    unsigned short*     h    = (unsigned short*)ws;     ws += (size_t)N * COUT * 2;     // 25.6 MB
    unsigned long long* brec = (unsigned long long*)ws; ws += (size_t)NB * BCAP * 8;    // 32.0 MB
    unsigned int*       srec = (unsigned int*)ws;       ws += (size_t)NB * BCAP * 4;    // 16.0 MB
    int2*               rinf = (int2*)ws;               ws += (size_t)N * 8;            // 0.8 MB
    float*              dis  = (float*)ws;              ws += (size_t)N * 4;
    int*                cur  = (int*)ws;                ws += (size_t)NB * 4;

    k_zero   <<<(NB + 255) / 256, 256, 0, stream>>>(cur, NB);
    k_part   <<<(E + EPB - 1) / EPB, 256, 0, stream>>>(ei, ew, cur, brec, E, NB);
    k_sortdeg<<<NB, 256, 0, stream>>>(brec, cur, srec, rinf, dis, N, srcshift);
    k_gemm   <<<(N + 127) / 128, 256, 0, stream>>>(X, W, dis, h, N);
    k_agg    <<<(N + 7) / 8, 256, 0, stream>>>(h, srec, rinf, dis, bias, out, N);
}

// Round 8
// 242.107 us; speedup vs baseline: 1.0204x; 1.0204x over previous
//
#include <hip/hip_runtime.h>

#define CIN 128
#define COUT 128
#define NB_MAX 512          // max buckets (N<=131072 at 256 nodes/bucket)
#define BCAP 10240          // records per bucket; E[bucket]=8192, sd~91 -> 22-sigma margin
#define EPB 8192            // edges per partition block (256 thr x 32)

typedef float f32x4 __attribute__((ext_vector_type(4)));   // native vec for nontemporal builtin

__device__ __forceinline__ unsigned short f2bf(float x) {
    unsigned int b = __float_as_uint(x);
    b += 0x7FFFu + ((b >> 16) & 1u);           // round-to-nearest-even
    return (unsigned short)(b >> 16);
}
__device__ __forceinline__ float bf2f_hi(unsigned int u) {      // high half of dword
    return __uint_as_float(u & 0xFFFF0000u);
}
__device__ __forceinline__ float bf2f_lo(unsigned int u) {      // low half of dword
    return __uint_as_float(u << 16);
}

// ---------------- zero bucket cursors ----------------
__global__ void k_zero(int* __restrict__ cursor, int NB) {
    int i = blockIdx.x * blockDim.x + threadIdx.x;
    if (i < NB) cursor[i] = 0;
}

// ---------------- LDS-staged radix partition by dst>>8 ----------------
__global__ __launch_bounds__(256) void k_part(const int* __restrict__ ei, const float* __restrict__ ew,
                                              int* __restrict__ cursor,
                                              unsigned long long* __restrict__ brec,
                                              int E, int NB) {
    __shared__ int hist[NB_MAX];
    __shared__ int base_[NB_MAX];
    int t = threadIdx.x;
    int chunk0 = blockIdx.x * EPB;
    bool vec_ok = ((E & 3) == 0);

    for (int i = t; i < NB; i += 256) hist[i] = 0;
    __syncthreads();

    // pass 1: chunk histogram (int4 dst reads: 4 edges per lane-instr)
    #pragma unroll
    for (int k = 0; k < EPB / 1024; ++k) {
        int e0 = chunk0 + (k * 256 + t) * 4;
        if (vec_ok && e0 + 3 < E) {
            int4 d4 = *(const int4*)(ei + E + e0);
            atomicAdd(&hist[d4.x >> 8], 1);
            atomicAdd(&hist[d4.y >> 8], 1);
            atomicAdd(&hist[d4.z >> 8], 1);
            atomicAdd(&hist[d4.w >> 8], 1);
        } else {
            for (int q = 0; q < 4; ++q) {
                int e = e0 + q;
                if (e < E) atomicAdd(&hist[ei[E + e] >> 8], 1);
            }
        }
    }
    __syncthreads();

    // reserve contiguous runs per bucket
    for (int i = t; i < NB; i += 256) {
        int c = hist[i];
        base_[i] = (c > 0) ? atomicAdd(&cursor[i], c) : 0;
        hist[i] = 0;                       // reuse as local cursor
    }
    __syncthreads();

#define PLACE(ss, dd, ww) do {                                                    \
        int b_ = (dd) >> 8;                                                       \
        unsigned int q_ = (unsigned int)((ww) * 32767.0f + 0.5f);                 \
        int lp_ = atomicAdd(&hist[b_], 1);                                        \
        int pos_ = base_[b_] + lp_;                                               \
        if (pos_ < BCAP)                                                          \
            brec[(size_t)b_ * BCAP + pos_] =                                      \
                ((unsigned long long)((dd) & 255) << 32) |                        \
                (((unsigned int)(ss) << 15) | q_);                                \
    } while (0)

    // pass 2: place records (int4/float4 edge reads)
    #pragma unroll
    for (int k = 0; k < EPB / 1024; ++k) {
        int e0 = chunk0 + (k * 256 + t) * 4;
        if (vec_ok && e0 + 3 < E) {
            int4 s4 = *(const int4*)(ei + e0);
            int4 d4 = *(const int4*)(ei + E + e0);
            float4 w4 = *(const float4*)(ew + e0);
            PLACE(s4.x, d4.x, w4.x);
            PLACE(s4.y, d4.y, w4.y);
            PLACE(s4.z, d4.z, w4.z);
            PLACE(s4.w, d4.w, w4.w);
        } else {
            for (int q = 0; q < 4; ++q) {
                int e = e0 + q;
                if (e < E) PLACE(ei[e], ei[E + e], ew[e]);
            }
        }
    }
#undef PLACE
}

// ---------------- per-bucket LDS counting sort -> exact CSR + dis ----------------
__global__ __launch_bounds__(256) void k_sortdeg(const unsigned long long* __restrict__ brec,
                                                 const int* __restrict__ cursor,
                                                 unsigned int* __restrict__ srec,
                                                 int2* __restrict__ rowinfo,
                                                 float* __restrict__ dis, int N) {
    __shared__ int histA[256];
    __shared__ int scanB[256];
    __shared__ int degq[256];
    __shared__ unsigned int stage[BCAP];   // 40 KB
    int t = threadIdx.x;
    int b = blockIdx.x;
    int cnt = min(cursor[b], BCAP);
    const unsigned long long* r = brec + (size_t)b * BCAP;

    histA[t] = 0; degq[t] = 0;
    __syncthreads();

    for (int j = t; j < cnt; j += 256) {
        unsigned long long v = r[j];
        int dl = (int)(v >> 32);
        atomicAdd(&histA[dl], 1);
        atomicAdd(&degq[dl], (int)((unsigned int)v & 0x7FFFu));
    }
    __syncthreads();

    int c = histA[t];
    scanB[t] = c;
    __syncthreads();
    #pragma unroll
    for (int off = 1; off < 256; off <<= 1) {
        int v = (t >= off) ? scanB[t - off] : 0;
        __syncthreads();
        scanB[t] += v;
        __syncthreads();
    }
    int excl = scanB[t] - c;

    int n = b * 256 + t;
    if (n < N) {
        dis[n] = rsqrtf(1.0f + (float)degq[t] * (1.0f / 32767.0f));
        rowinfo[n] = make_int2(b * BCAP + excl, c);
    }
    histA[t] = excl;                       // reuse as per-node cursor
    __syncthreads();

    for (int j = t; j < cnt; j += 256) {
        unsigned long long v = r[j];
        int dl = (int)(v >> 32);
        int pos = atomicAdd(&histA[dl], 1);
        stage[pos] = (unsigned int)v;
    }
    __syncthreads();

    unsigned int* so = srec + (size_t)b * BCAP;
    for (int j = t; j < cnt; j += 256) so[j] = stage[j];
}

// ---------------- GEMM: h'[n] = bf16( (X[n] @ W) * dis[n] ) ----------------
// 128x128 block tile, 8x8 per thread (as 4x4 split across 64-offset), K-block 16.
#define GK 16
#define LDP 132    // padded LDS row (floats): 16B-aligned rows, conflict-free inner reads
__global__ __launch_bounds__(256) void k_gemm(const float* __restrict__ X, const float* __restrict__ W,
                                              const float* __restrict__ dis,
                                              unsigned short* __restrict__ h, int N) {
    __shared__ float Xs[GK][LDP];   // k-major: Xs[k][node]
    __shared__ float Ws[GK][LDP];   // Ws[k][col]
    int t = threadIdx.x;
    int tx = t & 15;                // col split-tile: cols {tx*4+q, 64+tx*4+q}
    int ty = t >> 4;                // node split-tile: nodes {ty*4+i, 64+ty*4+i}
    int n0 = blockIdx.x * 128;

    float acc[8][8] = {};           // [node 0..3,64..67][col 0..3,64..67]

    for (int ko = 0; ko < CIN; ko += GK) {
        __syncthreads();
        // stage X (128 nodes x GK k), transposed into Xs[k][node]
        #pragma unroll
        for (int i = 0; i < 2; ++i) {
            int idx = t + i * 256;          // 0..511 float4s
            int node = idx >> 2;            // 4 float4 per node
            int kq = idx & 3;
            float4 v = make_float4(0.f, 0.f, 0.f, 0.f);
            if (n0 + node < N) v = *(const float4*)(X + (size_t)(n0 + node) * CIN + ko + kq * 4);
            Xs[kq * 4 + 0][node] = v.x;
            Xs[kq * 4 + 1][node] = v.y;
            Xs[kq * 4 + 2][node] = v.z;
            Xs[kq * 4 + 3][node] = v.w;
        }
        // stage W (GK rows x 128 cols)
        #pragma unroll
        for (int i = 0; i < 2; ++i) {
            int idx = t + i * 256;          // 0..511 float4s
            int kr = idx >> 5;              // 32 float4 per k-row
            int cq = idx & 31;
            float4 v = *(const float4*)(W + (size_t)(ko + kr) * COUT + cq * 4);
            *(float4*)(&Ws[kr][cq * 4]) = v;
        }
        __syncthreads();

        #pragma unroll
        for (int kk = 0; kk < GK; ++kk) {
            float x[8], w[8];
            *(float4*)&x[0] = *(const float4*)&Xs[kk][ty * 4];
            *(float4*)&x[4] = *(const float4*)&Xs[kk][64 + ty * 4];
            *(float4*)&w[0] = *(const float4*)&Ws[kk][tx * 4];
            *(float4*)&w[4] = *(const float4*)&Ws[kk][64 + tx * 4];
            #pragma unroll
            for (int i = 0; i < 8; ++i)
                #pragma unroll
                for (int q = 0; q < 8; ++q)
                    acc[i][q] += x[i] * w[q];
        }
    }

    // epilogue: scale by dis, pack bf16, store 8B per half-row
    #pragma unroll
    for (int i = 0; i < 8; ++i) {
        int node = n0 + ((i < 4) ? (ty * 4 + i) : (64 + ty * 4 + (i - 4)));
        if (node < N) {
            float dn = dis[node];
            uint2 p0, p1;
            p0.x = (unsigned int)f2bf(acc[i][0] * dn) | ((unsigned int)f2bf(acc[i][1] * dn) << 16);
            p0.y = (unsigned int)f2bf(acc[i][2] * dn) | ((unsigned int)f2bf(acc[i][3] * dn) << 16);
            p1.x = (unsigned int)f2bf(acc[i][4] * dn) | ((unsigned int)f2bf(acc[i][5] * dn) << 16);
            p1.y = (unsigned int)f2bf(acc[i][6] * dn) | ((unsigned int)f2bf(acc[i][7] * dn) << 16);
            *(uint2*)(h + (size_t)node * COUT + tx * 4)      = p0;
            *(uint2*)(h + (size_t)node * COUT + 64 + tx * 4) = p1;
        }
    }
}

// ---------------- aggregation: out[n] = dis[n]*(h'[n] + sum ew*h'[src]) + b ----------------
// 2 nodes per wave; 16 lanes per edge (uint4 = 8 bf16 channels per lane).
// Register-level double-buffer: two gather batches (8 x uint4) + records two
// batches ahead are in flight simultaneously -> ~2x MLP vs previous version.
__global__ __launch_bounds__(256) void k_agg(const unsigned short* __restrict__ h,
                                             const unsigned int* __restrict__ srec,
                                             const int2* __restrict__ rowinfo,
                                             const float* __restrict__ dis,
                                             const float* __restrict__ bias,
                                             float* __restrict__ out, int N) {
    int wave = threadIdx.x >> 6;
    int lane = threadIdx.x & 63;
    int slot = lane >> 4;            // 0..3: {nodeA,e0},{nodeA,e1},{nodeB,e0},{nodeB,e1}
    int sl   = slot & 1;             // edge parity within node
    int cl   = lane & 15;            // 16B group within row (8 bf16 channels)
    int node = blockIdx.x * 8 + wave * 2 + (slot >> 1);
    bool valid = node < N;
    int2 ri = valid ? rowinfo[node] : make_int2(0, 0);
    const unsigned int* r = srec + ri.x;
    int m = ri.y;
    const uint4* hu = (const uint4*)h;   // 16 uint4 per 128-channel row

    float a[8] = {0.f, 0.f, 0.f, 0.f, 0.f, 0.f, 0.f, 0.f};
    if (valid && sl == 0) {              // self-loop term (h' already carries dis[n])
        uint4 us = hu[(size_t)node * 16 + cl];
        a[0] = bf2f_lo(us.x); a[1] = bf2f_hi(us.x);
        a[2] = bf2f_lo(us.y); a[3] = bf2f_hi(us.y);
        a[4] = bf2f_lo(us.z); a[5] = bf2f_hi(us.z);
        a[6] = bf2f_lo(us.w); a[7] = bf2f_hi(us.w);
    }

#define LOAD_REC(dst, base_j) do {                                           \
        _Pragma("unroll")                                                    \
        for (int u = 0; u < 4; ++u) {                                        \
            int j_ = (base_j) + u * 2 + sl;                                  \
            dst[u] = (j_ < m) ? __builtin_nontemporal_load(r + j_) : 0u;     \
        } } while (0)

#define GATHER(vv, rr) do {                                                  \
        _Pragma("unroll")                                                    \
        for (int u = 0; u < 4; ++u)                                          \
            vv[u] = hu[(size_t)(rr[u] >> 15) * 16 + cl];                     \
        } while (0)

#define ACCUM(rr, vv) do {                                                   \
        _Pragma("unroll")                                                    \
        for (int u = 0; u < 4; ++u) {                                        \
            float w_ = (float)(rr[u] & 0x7FFFu) * (1.0f / 32767.0f);         \
            a[0] += w_ * bf2f_lo(vv[u].x); a[1] += w_ * bf2f_hi(vv[u].x);    \
            a[2] += w_ * bf2f_lo(vv[u].y); a[3] += w_ * bf2f_hi(vv[u].y);    \
            a[4] += w_ * bf2f_lo(vv[u].z); a[5] += w_ * bf2f_hi(vv[u].z);    \
            a[6] += w_ * bf2f_lo(vv[u].w); a[7] += w_ * bf2f_hi(vv[u].w);    \
        } } while (0)

    unsigned int rc0[4], rc1[4], rc2[4];
    uint4 v0[4], v1[4];

    LOAD_REC(rc0, 0);          // rec[batch k]
    LOAD_REC(rc1, 8);          // rec[batch k+1]
    GATHER(v0, rc0);           // data[batch k] in flight

    for (int jb = 0; jb < m; jb += 16) {
        GATHER(v1, rc1);             // data[k+1] in flight (8 gathers now outstanding)
        LOAD_REC(rc2, jb + 16);      // rec[k+2]
        ACCUM(rc0, v0);              // consume batch k
        GATHER(v0, rc2);             // data[k+2] in flight
        ACCUM(rc1, v1);              // consume batch k+1
        LOAD_REC(rc1, jb + 24);      // rec[k+3]
        #pragma unroll
        for (int u = 0; u < 4; ++u) rc0[u] = rc2[u];
    }
#undef LOAD_REC
#undef GATHER
#undef ACCUM

    #pragma unroll
    for (int i = 0; i < 8; ++i) a[i] += __shfl_xor(a[i], 16);   // combine edge-parity pair

    if (valid && sl == 0) {
        float dn = dis[node];
        float4 b0 = *(const float4*)(bias + cl * 8);
        float4 b1 = *(const float4*)(bias + cl * 8 + 4);
        f32x4 o0 = {a[0] * dn + b0.x, a[1] * dn + b0.y, a[2] * dn + b0.z, a[3] * dn + b0.w};
        f32x4 o1 = {a[4] * dn + b1.x, a[5] * dn + b1.y, a[6] * dn + b1.z, a[7] * dn + b1.w};
        f32x4* op = (f32x4*)(out + (size_t)node * COUT + cl * 8);
        __builtin_nontemporal_store(o0, op);        // write-once: keep out of L2
        __builtin_nontemporal_store(o1, op + 1);
    }
}

// ---------------- launch ----------------
extern "C" void kernel_launch(void* const* d_in, const int* in_sizes, int n_in,
                              void* d_out, int out_size, void* d_ws, size_t ws_size,
                              hipStream_t stream) {
    const float* X    = (const float*)d_in[0];
    const int*   ei   = (const int*)d_in[1];
    const float* ew   = (const float*)d_in[2];
    const float* W    = (const float*)d_in[3];
    const float* bias = (const float*)d_in[4];
    float* out = (float*)d_out;

    int E = in_sizes[2];            // edge_weight count
    int N = out_size / COUT;        // B == 1
    int NB = (N + 255) >> 8;        // buckets of 256 nodes

    // workspace carve-up (~75 MB)
    char* ws = (char*)d_ws;
    unsigned short*     h    = (unsigned short*)ws;     ws += (size_t)N * COUT * 2;     // 25.6 MB
    unsigned long long* brec = (unsigned long long*)ws; ws += (size_t)NB * BCAP * 8;    // 32.0 MB
    unsigned int*       srec = (unsigned int*)ws;       ws += (size_t)NB * BCAP * 4;    // 16.0 MB
    int2*               rinf = (int2*)ws;               ws += (size_t)N * 8;            // 0.8 MB
    float*              dis  = (float*)ws;              ws += (size_t)N * 4;
    int*                cur  = (int*)ws;                ws += (size_t)NB * 4;

    k_zero   <<<(NB + 255) / 256, 256, 0, stream>>>(cur, NB);
    k_part   <<<(E + EPB - 1) / EPB, 256, 0, stream>>>(ei, ew, cur, brec, E, NB);
    k_sortdeg<<<NB, 256, 0, stream>>>(brec, cur, srec, rinf, dis, N);
    k_gemm   <<<(N + 127) / 128, 256, 0, stream>>>(X, W, dis, h, N);
    k_agg    <<<(N + 7) / 8, 256, 0, stream>>>(h, srec, rinf, dis, bias, out, N);
}

// Round 9
// 242.013 us; speedup vs baseline: 1.0208x; 1.0004x over previous
//
#include <hip/hip_runtime.h>

#define CIN 128
#define COUT 128
#define NB_MAX 512          // max buckets (N<=131072 at 256 nodes/bucket)
#define BCAP 10240          // records per bucket; E[bucket]=8192, sd~91 -> 22-sigma margin
#define EPB 8192            // edges per partition block (256 thr x 32)

typedef float f32x4 __attribute__((ext_vector_type(4)));   // native vec for nontemporal builtin

__device__ __forceinline__ unsigned short f2bf(float x) {
    unsigned int b = __float_as_uint(x);
    b += 0x7FFFu + ((b >> 16) & 1u);           // round-to-nearest-even
    return (unsigned short)(b >> 16);
}
__device__ __forceinline__ float bf2f_hi(unsigned int u) {      // high half of dword
    return __uint_as_float(u & 0xFFFF0000u);
}
__device__ __forceinline__ float bf2f_lo(unsigned int u) {      // low half of dword
    return __uint_as_float(u << 16);
}

// ---------------- zero bucket cursors ----------------
__global__ void k_zero(int* __restrict__ cursor, int NB) {
    int i = blockIdx.x * blockDim.x + threadIdx.x;
    if (i < NB) cursor[i] = 0;
}

// ---------------- LDS-staged radix partition by dst>>8 ----------------
__global__ __launch_bounds__(256) void k_part(const int* __restrict__ ei, const float* __restrict__ ew,
                                              int* __restrict__ cursor,
                                              unsigned long long* __restrict__ brec,
                                              int E, int NB) {
    __shared__ int hist[NB_MAX];
    __shared__ int base_[NB_MAX];
    int t = threadIdx.x;
    int chunk0 = blockIdx.x * EPB;
    bool vec_ok = ((E & 3) == 0);

    for (int i = t; i < NB; i += 256) hist[i] = 0;
    __syncthreads();

    // pass 1: chunk histogram (int4 dst reads: 4 edges per lane-instr)
    #pragma unroll
    for (int k = 0; k < EPB / 1024; ++k) {
        int e0 = chunk0 + (k * 256 + t) * 4;
        if (vec_ok && e0 + 3 < E) {
            int4 d4 = *(const int4*)(ei + E + e0);
            atomicAdd(&hist[d4.x >> 8], 1);
            atomicAdd(&hist[d4.y >> 8], 1);
            atomicAdd(&hist[d4.z >> 8], 1);
            atomicAdd(&hist[d4.w >> 8], 1);
        } else {
            for (int q = 0; q < 4; ++q) {
                int e = e0 + q;
                if (e < E) atomicAdd(&hist[ei[E + e] >> 8], 1);
            }
        }
    }
    __syncthreads();

    // reserve contiguous runs per bucket
    for (int i = t; i < NB; i += 256) {
        int c = hist[i];
        base_[i] = (c > 0) ? atomicAdd(&cursor[i], c) : 0;
        hist[i] = 0;                       // reuse as local cursor
    }
    __syncthreads();

#define PLACE(ss, dd, ww) do {                                                    \
        int b_ = (dd) >> 8;                                                       \
        unsigned int q_ = (unsigned int)((ww) * 32767.0f + 0.5f);                 \
        int lp_ = atomicAdd(&hist[b_], 1);                                        \
        int pos_ = base_[b_] + lp_;                                               \
        if (pos_ < BCAP)                                                          \
            brec[(size_t)b_ * BCAP + pos_] =                                      \
                ((unsigned long long)((dd) & 255) << 32) |                        \
                (((unsigned int)(ss) << 15) | q_);                                \
    } while (0)

    // pass 2: place records (int4/float4 edge reads)
    #pragma unroll
    for (int k = 0; k < EPB / 1024; ++k) {
        int e0 = chunk0 + (k * 256 + t) * 4;
        if (vec_ok && e0 + 3 < E) {
            int4 s4 = *(const int4*)(ei + e0);
            int4 d4 = *(const int4*)(ei + E + e0);
            float4 w4 = *(const float4*)(ew + e0);
            PLACE(s4.x, d4.x, w4.x);
            PLACE(s4.y, d4.y, w4.y);
            PLACE(s4.z, d4.z, w4.z);
            PLACE(s4.w, d4.w, w4.w);
        } else {
            for (int q = 0; q < 4; ++q) {
                int e = e0 + q;
                if (e < E) PLACE(ei[e], ei[E + e], ew[e]);
            }
        }
    }
#undef PLACE
}

// ---------------- per-bucket LDS counting sort -> exact CSR + dis ----------------
__global__ __launch_bounds__(256) void k_sortdeg(const unsigned long long* __restrict__ brec,
                                                 const int* __restrict__ cursor,
                                                 unsigned int* __restrict__ srec,
                                                 int2* __restrict__ rowinfo,
                                                 float* __restrict__ dis, int N) {
    __shared__ int histA[256];
    __shared__ int scanB[256];
    __shared__ int degq[256];
    __shared__ unsigned int stage[BCAP];   // 40 KB
    int t = threadIdx.x;
    int b = blockIdx.x;
    int cnt = min(cursor[b], BCAP);
    const unsigned long long* r = brec + (size_t)b * BCAP;

    histA[t] = 0; degq[t] = 0;
    __syncthreads();

    for (int j = t; j < cnt; j += 256) {
        unsigned long long v = r[j];
        int dl = (int)(v >> 32);
        atomicAdd(&histA[dl], 1);
        atomicAdd(&degq[dl], (int)((unsigned int)v & 0x7FFFu));
    }
    __syncthreads();

    int c = histA[t];
    scanB[t] = c;
    __syncthreads();
    #pragma unroll
    for (int off = 1; off < 256; off <<= 1) {
        int v = (t >= off) ? scanB[t - off] : 0;
        __syncthreads();
        scanB[t] += v;
        __syncthreads();
    }
    int excl = scanB[t] - c;

    int n = b * 256 + t;
    if (n < N) {
        dis[n] = rsqrtf(1.0f + (float)degq[t] * (1.0f / 32767.0f));
        rowinfo[n] = make_int2(b * BCAP + excl, c);
    }
    histA[t] = excl;                       // reuse as per-node cursor
    __syncthreads();

    for (int j = t; j < cnt; j += 256) {
        unsigned long long v = r[j];
        int dl = (int)(v >> 32);
        int pos = atomicAdd(&histA[dl], 1);
        stage[pos] = (unsigned int)v;
    }
    __syncthreads();

    unsigned int* so = srec + (size_t)b * BCAP;
    for (int j = t; j < cnt; j += 256) so[j] = stage[j];
}

// ---------------- GEMM: h'[n] = bf16( (X[n] @ W) * dis[n] ), split into 2 channel planes ----
// plane p holds channels [p*64, p*64+64) as [N][64] bf16 (128 B rows).
#define GK 16
#define LDP 132    // padded LDS row (floats): 16B-aligned rows, conflict-free inner reads
__global__ __launch_bounds__(256) void k_gemm(const float* __restrict__ X, const float* __restrict__ W,
                                              const float* __restrict__ dis,
                                              unsigned short* __restrict__ h, int N) {
    __shared__ float Xs[GK][LDP];   // k-major: Xs[k][node]
    __shared__ float Ws[GK][LDP];   // Ws[k][col]
    int t = threadIdx.x;
    int tx = t & 15;                // col split-tile: cols {tx*4+q, 64+tx*4+q}
    int ty = t >> 4;                // node split-tile: nodes {ty*4+i, 64+ty*4+i}
    int n0 = blockIdx.x * 128;

    float acc[8][8] = {};           // [node 0..3,64..67][col 0..3,64..67]

    for (int ko = 0; ko < CIN; ko += GK) {
        __syncthreads();
        // stage X (128 nodes x GK k), transposed into Xs[k][node]
        #pragma unroll
        for (int i = 0; i < 2; ++i) {
            int idx = t + i * 256;          // 0..511 float4s
            int node = idx >> 2;            // 4 float4 per node
            int kq = idx & 3;
            float4 v = make_float4(0.f, 0.f, 0.f, 0.f);
            if (n0 + node < N) v = *(const float4*)(X + (size_t)(n0 + node) * CIN + ko + kq * 4);
            Xs[kq * 4 + 0][node] = v.x;
            Xs[kq * 4 + 1][node] = v.y;
            Xs[kq * 4 + 2][node] = v.z;
            Xs[kq * 4 + 3][node] = v.w;
        }
        // stage W (GK rows x 128 cols)
        #pragma unroll
        for (int i = 0; i < 2; ++i) {
            int idx = t + i * 256;          // 0..511 float4s
            int kr = idx >> 5;              // 32 float4 per k-row
            int cq = idx & 31;
            float4 v = *(const float4*)(W + (size_t)(ko + kr) * COUT + cq * 4);
            *(float4*)(&Ws[kr][cq * 4]) = v;
        }
        __syncthreads();

        #pragma unroll
        for (int kk = 0; kk < GK; ++kk) {
            float x[8], w[8];
            *(float4*)&x[0] = *(const float4*)&Xs[kk][ty * 4];
            *(float4*)&x[4] = *(const float4*)&Xs[kk][64 + ty * 4];
            *(float4*)&w[0] = *(const float4*)&Ws[kk][tx * 4];
            *(float4*)&w[4] = *(const float4*)&Ws[kk][64 + tx * 4];
            #pragma unroll
            for (int i = 0; i < 8; ++i)
                #pragma unroll
                for (int q = 0; q < 8; ++q)
                    acc[i][q] += x[i] * w[q];
        }
    }

    // epilogue: scale by dis, pack bf16, store into the two channel planes
    size_t plane1 = (size_t)N * 64;
    #pragma unroll
    for (int i = 0; i < 8; ++i) {
        int node = n0 + ((i < 4) ? (ty * 4 + i) : (64 + ty * 4 + (i - 4)));
        if (node < N) {
            float dn = dis[node];
            uint2 p0, p1;
            p0.x = (unsigned int)f2bf(acc[i][0] * dn) | ((unsigned int)f2bf(acc[i][1] * dn) << 16);
            p0.y = (unsigned int)f2bf(acc[i][2] * dn) | ((unsigned int)f2bf(acc[i][3] * dn) << 16);
            p1.x = (unsigned int)f2bf(acc[i][4] * dn) | ((unsigned int)f2bf(acc[i][5] * dn) << 16);
            p1.y = (unsigned int)f2bf(acc[i][6] * dn) | ((unsigned int)f2bf(acc[i][7] * dn) << 16);
            *(uint2*)(h + (size_t)node * 64 + tx * 4)           = p0;   // plane 0
            *(uint2*)(h + plane1 + (size_t)node * 64 + tx * 4)  = p1;   // plane 1
        }
    }
}

// ---------------- aggregation (one 64-channel plane per launch) ----------------
// 2 nodes per wave; per node 4 edge slots x 8 lanes (uint4 = 8 bf16 channels).
// One gather instr covers 8 edges (128 B rows from a 12.8 MB plane).
// Records prefetched one batch ahead; 4 uint4 gathers in flight per lane pair.
__global__ __launch_bounds__(256) void k_agg(const unsigned short* __restrict__ h,
                                             const unsigned int* __restrict__ srec,
                                             const int2* __restrict__ rowinfo,
                                             const float* __restrict__ dis,
                                             const float* __restrict__ bias,
                                             float* __restrict__ out, int N, int plane) {
    int wave = threadIdx.x >> 6;
    int lane = threadIdx.x & 63;
    int grp  = lane >> 5;            // which node of the pair
    int l32  = lane & 31;
    int slot = l32 >> 3;             // edge slot 0..3
    int cl   = l32 & 7;              // 16B group within 128 B row (8 bf16 channels)
    int node = blockIdx.x * 8 + wave * 2 + grp;
    bool valid = node < N;
    int2 ri = valid ? rowinfo[node] : make_int2(0, 0);
    const unsigned int* r = srec + ri.x;
    int m = ri.y;
    const uint4* hu = (const uint4*)(h + (size_t)plane * N * 64);   // 8 uint4 per 64-ch row

    float a[8] = {0.f, 0.f, 0.f, 0.f, 0.f, 0.f, 0.f, 0.f};
    if (valid && slot == 0) {            // self-loop term (h' already carries dis[n])
        uint4 us = hu[(size_t)node * 8 + cl];
        a[0] = bf2f_lo(us.x); a[1] = bf2f_hi(us.x);
        a[2] = bf2f_lo(us.y); a[3] = bf2f_hi(us.y);
        a[4] = bf2f_lo(us.z); a[5] = bf2f_hi(us.z);
        a[6] = bf2f_lo(us.w); a[7] = bf2f_hi(us.w);
    }

#define LOAD_REC(dst, base_j) do {                                           \
        _Pragma("unroll")                                                    \
        for (int u = 0; u < 2; ++u) {                                        \
            int j_ = (base_j) + u * 4 + slot;                                \
            dst[u] = (j_ < m) ? __builtin_nontemporal_load(r + j_) : 0u;     \
        } } while (0)

    unsigned int rrc[2];
    LOAD_REC(rrc, 0);
    for (int jb = 0; jb < m; jb += 8) {
        unsigned int rrn[2];
        LOAD_REC(rrn, jb + 8);               // prefetch next batch's records
        uint4 v0 = hu[(size_t)(rrc[0] >> 15) * 8 + cl];   // both gathers in flight
        uint4 v1 = hu[(size_t)(rrc[1] >> 15) * 8 + cl];
        float w0 = (float)(rrc[0] & 0x7FFFu) * (1.0f / 32767.0f);
        float w1 = (float)(rrc[1] & 0x7FFFu) * (1.0f / 32767.0f);
        a[0] += w0 * bf2f_lo(v0.x); a[1] += w0 * bf2f_hi(v0.x);
        a[2] += w0 * bf2f_lo(v0.y); a[3] += w0 * bf2f_hi(v0.y);
        a[4] += w0 * bf2f_lo(v0.z); a[5] += w0 * bf2f_hi(v0.z);
        a[6] += w0 * bf2f_lo(v0.w); a[7] += w0 * bf2f_hi(v0.w);
        a[0] += w1 * bf2f_lo(v1.x); a[1] += w1 * bf2f_hi(v1.x);
        a[2] += w1 * bf2f_lo(v1.y); a[3] += w1 * bf2f_hi(v1.y);
        a[4] += w1 * bf2f_lo(v1.z); a[5] += w1 * bf2f_hi(v1.z);
        a[6] += w1 * bf2f_lo(v1.w); a[7] += w1 * bf2f_hi(v1.w);
        rrc[0] = rrn[0]; rrc[1] = rrn[1];
    }
#undef LOAD_REC

    // combine the 4 edge slots within each 32-lane node group
    #pragma unroll
    for (int i = 0; i < 8; ++i) {
        a[i] += __shfl_xor(a[i], 8);
        a[i] += __shfl_xor(a[i], 16);
    }

    if (valid && slot == 0) {
        float dn = dis[node];
        int c0 = plane * 64 + cl * 8;
        float4 b0 = *(const float4*)(bias + c0);
        float4 b1 = *(const float4*)(bias + c0 + 4);
        f32x4 o0 = {a[0] * dn + b0.x, a[1] * dn + b0.y, a[2] * dn + b0.z, a[3] * dn + b0.w};
        f32x4 o1 = {a[4] * dn + b1.x, a[5] * dn + b1.y, a[6] * dn + b1.z, a[7] * dn + b1.w};
        f32x4* op = (f32x4*)(out + (size_t)node * COUT + c0);
        __builtin_nontemporal_store(o0, op);        // write-once: keep out of L2
        __builtin_nontemporal_store(o1, op + 1);
    }
}

// ---------------- launch ----------------
extern "C" void kernel_launch(void* const* d_in, const int* in_sizes, int n_in,
                              void* d_out, int out_size, void* d_ws, size_t ws_size,
                              hipStream_t stream) {
    const float* X    = (const float*)d_in[0];
    const int*   ei   = (const int*)d_in[1];
    const float* ew   = (const float*)d_in[2];
    const float* W    = (const float*)d_in[3];
    const float* bias = (const float*)d_in[4];
    float* out = (float*)d_out;

    int E = in_sizes[2];            // edge_weight count
    int N = out_size / COUT;        // B == 1
    int NB = (N + 255) >> 8;        // buckets of 256 nodes

    // workspace carve-up (~75 MB)
    char* ws = (char*)d_ws;
    unsigned short*     h    = (unsigned short*)ws;     ws += (size_t)N * COUT * 2;     // 25.6 MB (2 planes)
    unsigned long long* brec = (unsigned long long*)ws; ws += (size_t)NB * BCAP * 8;    // 32.0 MB
    unsigned int*       srec = (unsigned int*)ws;       ws += (size_t)NB * BCAP * 4;    // 16.0 MB
    int2*               rinf = (int2*)ws;               ws += (size_t)N * 8;            // 0.8 MB
    float*              dis  = (float*)ws;              ws += (size_t)N * 4;
    int*                cur  = (int*)ws;                ws += (size_t)NB * 4;

    k_zero   <<<(NB + 255) / 256, 256, 0, stream>>>(cur, NB);
    k_part   <<<(E + EPB - 1) / EPB, 256, 0, stream>>>(ei, ew, cur, brec, E, NB);
    k_sortdeg<<<NB, 256, 0, stream>>>(brec, cur, srec, rinf, dis, N);
    k_gemm   <<<(N + 127) / 128, 256, 0, stream>>>(X, W, dis, h, N);
    k_agg    <<<(N + 7) / 8, 256, 0, stream>>>(h, srec, rinf, dis, bias, out, N, 0);
    k_agg    <<<(N + 7) / 8, 256, 0, stream>>>(h, srec, rinf, dis, bias, out, N, 1);
}

// Round 10
// 205.185 us; speedup vs baseline: 1.2040x; 1.1795x over previous
//
#include <hip/hip_runtime.h>

#define CIN 128
#define COUT 128
#define NB_MAX 512          // max buckets (N<=131072 at 256 nodes/bucket)
#define BCAP 10240          // records per bucket; E[bucket]=8192, sd~91 -> 22-sigma margin
#define EPB 8192            // edges per partition block (256 thr x 32)

typedef float f32x4 __attribute__((ext_vector_type(4)));   // native vec (nontemporal + MFMA acc)
typedef short bf16x8 __attribute__((ext_vector_type(8)));  // MFMA A/B fragment (8 bf16)

__device__ __forceinline__ unsigned short f2bf(float x) {
    unsigned int b = __float_as_uint(x);
    b += 0x7FFFu + ((b >> 16) & 1u);           // round-to-nearest-even
    return (unsigned short)(b >> 16);
}
__device__ __forceinline__ float bf2f_hi(unsigned int u) {      // high half of dword
    return __uint_as_float(u & 0xFFFF0000u);
}
__device__ __forceinline__ float bf2f_lo(unsigned int u) {      // low half of dword
    return __uint_as_float(u << 16);
}

// ---------------- zero bucket cursors ----------------
__global__ void k_zero(int* __restrict__ cursor, int NB) {
    int i = blockIdx.x * blockDim.x + threadIdx.x;
    if (i < NB) cursor[i] = 0;
}

// ---------------- LDS-staged radix partition by dst>>8 ----------------
__global__ __launch_bounds__(256) void k_part(const int* __restrict__ ei, const float* __restrict__ ew,
                                              int* __restrict__ cursor,
                                              unsigned long long* __restrict__ brec,
                                              int E, int NB) {
    __shared__ int hist[NB_MAX];
    __shared__ int base_[NB_MAX];
    int t = threadIdx.x;
    int chunk0 = blockIdx.x * EPB;
    bool vec_ok = ((E & 3) == 0);

    for (int i = t; i < NB; i += 256) hist[i] = 0;
    __syncthreads();

    #pragma unroll
    for (int k = 0; k < EPB / 1024; ++k) {
        int e0 = chunk0 + (k * 256 + t) * 4;
        if (vec_ok && e0 + 3 < E) {
            int4 d4 = *(const int4*)(ei + E + e0);
            atomicAdd(&hist[d4.x >> 8], 1);
            atomicAdd(&hist[d4.y >> 8], 1);
            atomicAdd(&hist[d4.z >> 8], 1);
            atomicAdd(&hist[d4.w >> 8], 1);
        } else {
            for (int q = 0; q < 4; ++q) {
                int e = e0 + q;
                if (e < E) atomicAdd(&hist[ei[E + e] >> 8], 1);
            }
        }
    }
    __syncthreads();

    for (int i = t; i < NB; i += 256) {
        int c = hist[i];
        base_[i] = (c > 0) ? atomicAdd(&cursor[i], c) : 0;
        hist[i] = 0;                       // reuse as local cursor
    }
    __syncthreads();

#define PLACE(ss, dd, ww) do {                                                    \
        int b_ = (dd) >> 8;                                                       \
        unsigned int q_ = (unsigned int)((ww) * 32767.0f + 0.5f);                 \
        int lp_ = atomicAdd(&hist[b_], 1);                                        \
        int pos_ = base_[b_] + lp_;                                               \
        if (pos_ < BCAP)                                                          \
            brec[(size_t)b_ * BCAP + pos_] =                                      \
                ((unsigned long long)((dd) & 255) << 32) |                        \
                (((unsigned int)(ss) << 15) | q_);                                \
    } while (0)

    #pragma unroll
    for (int k = 0; k < EPB / 1024; ++k) {
        int e0 = chunk0 + (k * 256 + t) * 4;
        if (vec_ok && e0 + 3 < E) {
            int4 s4 = *(const int4*)(ei + e0);
            int4 d4 = *(const int4*)(ei + E + e0);
            float4 w4 = *(const float4*)(ew + e0);
            PLACE(s4.x, d4.x, w4.x);
            PLACE(s4.y, d4.y, w4.y);
            PLACE(s4.z, d4.z, w4.z);
            PLACE(s4.w, d4.w, w4.w);
        } else {
            for (int q = 0; q < 4; ++q) {
                int e = e0 + q;
                if (e < E) PLACE(ei[e], ei[E + e], ew[e]);
            }
        }
    }
#undef PLACE
}

// ---------------- per-bucket LDS counting sort -> exact CSR + dis ----------------
__global__ __launch_bounds__(256) void k_sortdeg(const unsigned long long* __restrict__ brec,
                                                 const int* __restrict__ cursor,
                                                 unsigned int* __restrict__ srec,
                                                 int2* __restrict__ rowinfo,
                                                 float* __restrict__ dis, int N) {
    __shared__ int histA[256];
    __shared__ int scanB[256];
    __shared__ int degq[256];
    __shared__ unsigned int stage[BCAP];   // 40 KB
    int t = threadIdx.x;
    int b = blockIdx.x;
    int cnt = min(cursor[b], BCAP);
    const unsigned long long* r = brec + (size_t)b * BCAP;

    histA[t] = 0; degq[t] = 0;
    __syncthreads();

    for (int j = t; j < cnt; j += 256) {
        unsigned long long v = r[j];
        int dl = (int)(v >> 32);
        atomicAdd(&histA[dl], 1);
        atomicAdd(&degq[dl], (int)((unsigned int)v & 0x7FFFu));
    }
    __syncthreads();

    int c = histA[t];
    scanB[t] = c;
    __syncthreads();
    #pragma unroll
    for (int off = 1; off < 256; off <<= 1) {
        int v = (t >= off) ? scanB[t - off] : 0;
        __syncthreads();
        scanB[t] += v;
        __syncthreads();
    }
    int excl = scanB[t] - c;

    int n = b * 256 + t;
    if (n < N) {
        dis[n] = rsqrtf(1.0f + (float)degq[t] * (1.0f / 32767.0f));
        rowinfo[n] = make_int2(b * BCAP + excl, c);
    }
    histA[t] = excl;                       // reuse as per-node cursor
    __syncthreads();

    for (int j = t; j < cnt; j += 256) {
        unsigned long long v = r[j];
        int dl = (int)(v >> 32);
        int pos = atomicAdd(&histA[dl], 1);
        stage[pos] = (unsigned int)v;
    }
    __syncthreads();

    unsigned int* so = srec + (size_t)b * BCAP;
    for (int j = t; j < cnt; j += 256) so[j] = stage[j];
}

// ---------------- W -> B-fragment layout (bf16), one small launch ----------------
// WB[((ct*4+ks)*64+lane)*8+j] = bf16( W[ks*32+(lane>>4)*8+j][ct*16+(lane&15)] )
__global__ void k_wprep(const float* __restrict__ W, unsigned short* __restrict__ WB) {
    int t = threadIdx.x;
    for (int pos = t; pos < 8 * 4 * 64 * 8; pos += 256) {
        int j    = pos & 7;
        int lane = (pos >> 3) & 63;
        int ks   = (pos >> 9) & 3;
        int ct   = pos >> 11;
        int k = ks * 32 + (lane >> 4) * 8 + j;
        int c = ct * 16 + (lane & 15);
        WB[pos] = f2bf(W[k * COUT + c]);
    }
}

// ---------------- GEMM via MFMA: h'[n] = bf16( (X[n] @ W) * dis[n] ), 2 channel planes ----
// 64 nodes/block, 4 waves; wave w: 16 nodes x 128 cols = 8 col-tiles x 4 K-steps
// of v_mfma_f32_16x16x32_bf16. A-frags straight from global X (f32->bf16 in reg);
// B-frags from LDS (pre-packed fragment layout, linear = conflict-free).
__global__ __launch_bounds__(256) void k_gemm(const float* __restrict__ X,
                                              const unsigned short* __restrict__ WB,
                                              const float* __restrict__ dis,
                                              unsigned short* __restrict__ h, int N) {
    __shared__ unsigned short WBs[8 * 4 * 64 * 8];   // 32 KB
    __shared__ unsigned short outs[4][16 * 128];     // 16 KB (per-wave D staging)
    int t = threadIdx.x;
    int w = t >> 6, l = t & 63;
    int n0 = blockIdx.x * 64;

    // stage WB linearly (2048 uint4, 8 per thread)
    {
        const uint4* src = (const uint4*)WB;
        uint4* dst = (uint4*)WBs;
        #pragma unroll
        for (int i = 0; i < 8; ++i) dst[t + i * 256] = src[t + i * 256];
    }

    // A fragments: lane l covers row n0+w*16+(l&15), k = ks*32 + (l>>4)*8 + 0..7
    int rowg = n0 + w * 16 + (l & 15);
    int rcl = min(rowg, N - 1);
    int kbase = (l >> 4) * 8;
    bf16x8 afrag[4];
    #pragma unroll
    for (int ks = 0; ks < 4; ++ks) {
        const float* xp = X + (size_t)rcl * CIN + ks * 32 + kbase;
        float4 x0 = *(const float4*)xp;
        float4 x1 = *(const float4*)(xp + 4);
        bf16x8 a;
        a[0] = (short)f2bf(x0.x); a[1] = (short)f2bf(x0.y);
        a[2] = (short)f2bf(x0.z); a[3] = (short)f2bf(x0.w);
        a[4] = (short)f2bf(x1.x); a[5] = (short)f2bf(x1.y);
        a[6] = (short)f2bf(x1.z); a[7] = (short)f2bf(x1.w);
        afrag[ks] = a;
    }

    __syncthreads();   // WBs ready

    f32x4 acc[8];
    #pragma unroll
    for (int ct = 0; ct < 8; ++ct) acc[ct] = (f32x4){0.f, 0.f, 0.f, 0.f};

    const bf16x8* wb = (const bf16x8*)WBs;   // index (ct*4+ks)*64 + l
    #pragma unroll
    for (int ct = 0; ct < 8; ++ct) {
        #pragma unroll
        for (int ks = 0; ks < 4; ++ks) {
            bf16x8 b = wb[(ct * 4 + ks) * 64 + l];
            acc[ct] = __builtin_amdgcn_mfma_f32_16x16x32_bf16(afrag[ks], b, acc[ct], 0, 0, 0);
        }
    }

    // D layout: lane l, reg r -> row (l>>4)*4+r, col l&15 (m89-verified).
    // Scale by dis, pack bf16 into per-wave LDS tile, then store full 128B lines.
    int rb = n0 + w * 16 + (l >> 4) * 4;             // dis padded by 64 floats -> safe
    float4 d4 = *(const float4*)(dis + rb);
    unsigned short* ow = &outs[w][0];
    #pragma unroll
    for (int ct = 0; ct < 8; ++ct) {
        int ocol = ct * 16 + (l & 15);
        int orow = (l >> 4) * 4;
        ow[(orow + 0) * 128 + ocol] = f2bf(acc[ct][0] * d4.x);
        ow[(orow + 1) * 128 + ocol] = f2bf(acc[ct][1] * d4.y);
        ow[(orow + 2) * 128 + ocol] = f2bf(acc[ct][2] * d4.z);
        ow[(orow + 3) * 128 + ocol] = f2bf(acc[ct][3] * d4.w);
    }

    size_t plane1 = (size_t)N * 64;
    #pragma unroll
    for (int i = 0; i < 4; ++i) {
        int off = i * 1024 + l * 16;                 // byte offset in wave's 4KB tile
        int orow = off >> 8;
        int col = (off & 255) >> 1;                  // 0..127, multiples of 8
        int node = n0 + w * 16 + orow;
        if (node < N) {
            uint4 v = *(const uint4*)((const char*)ow + off);
            unsigned short* dst = h + (col < 64 ? 0 : plane1) + (size_t)node * 64 + (col & 63);
            *(uint4*)dst = v;
        }
    }
}

// ---------------- aggregation (one 64-channel plane per launch) ----------------
__global__ __launch_bounds__(256) void k_agg(const unsigned short* __restrict__ h,
                                             const unsigned int* __restrict__ srec,
                                             const int2* __restrict__ rowinfo,
                                             const float* __restrict__ dis,
                                             const float* __restrict__ bias,
                                             float* __restrict__ out, int N, int plane) {
    int wave = threadIdx.x >> 6;
    int lane = threadIdx.x & 63;
    int grp  = lane >> 5;            // which node of the pair
    int l32  = lane & 31;
    int slot = l32 >> 3;             // edge slot 0..3
    int cl   = l32 & 7;              // 16B group within 128 B row (8 bf16 channels)
    int node = blockIdx.x * 8 + wave * 2 + grp;
    bool valid = node < N;
    int2 ri = valid ? rowinfo[node] : make_int2(0, 0);
    const unsigned int* r = srec + ri.x;
    int m = ri.y;
    const uint4* hu = (const uint4*)(h + (size_t)plane * N * 64);   // 8 uint4 per 64-ch row

    float a[8] = {0.f, 0.f, 0.f, 0.f, 0.f, 0.f, 0.f, 0.f};
    if (valid && slot == 0) {            // self-loop term (h' already carries dis[n])
        uint4 us = hu[(size_t)node * 8 + cl];
        a[0] = bf2f_lo(us.x); a[1] = bf2f_hi(us.x);
        a[2] = bf2f_lo(us.y); a[3] = bf2f_hi(us.y);
        a[4] = bf2f_lo(us.z); a[5] = bf2f_hi(us.z);
        a[6] = bf2f_lo(us.w); a[7] = bf2f_hi(us.w);
    }

#define LOAD_REC(dst, base_j) do {                                           \
        _Pragma("unroll")                                                    \
        for (int u = 0; u < 2; ++u) {                                        \
            int j_ = (base_j) + u * 4 + slot;                                \
            dst[u] = (j_ < m) ? __builtin_nontemporal_load(r + j_) : 0u;     \
        } } while (0)

    unsigned int rrc[2];
    LOAD_REC(rrc, 0);
    for (int jb = 0; jb < m; jb += 8) {
        unsigned int rrn[2];
        LOAD_REC(rrn, jb + 8);               // prefetch next batch's records
        uint4 v0 = hu[(size_t)(rrc[0] >> 15) * 8 + cl];   // both gathers in flight
        uint4 v1 = hu[(size_t)(rrc[1] >> 15) * 8 + cl];
        float w0 = (float)(rrc[0] & 0x7FFFu) * (1.0f / 32767.0f);
        float w1 = (float)(rrc[1] & 0x7FFFu) * (1.0f / 32767.0f);
        a[0] += w0 * bf2f_lo(v0.x); a[1] += w0 * bf2f_hi(v0.x);
        a[2] += w0 * bf2f_lo(v0.y); a[3] += w0 * bf2f_hi(v0.y);
        a[4] += w0 * bf2f_lo(v0.z); a[5] += w0 * bf2f_hi(v0.z);
        a[6] += w0 * bf2f_lo(v0.w); a[7] += w0 * bf2f_hi(v0.w);
        a[0] += w1 * bf2f_lo(v1.x); a[1] += w1 * bf2f_hi(v1.x);
        a[2] += w1 * bf2f_lo(v1.y); a[3] += w1 * bf2f_hi(v1.y);
        a[4] += w1 * bf2f_lo(v1.z); a[5] += w1 * bf2f_hi(v1.z);
        a[6] += w1 * bf2f_lo(v1.w); a[7] += w1 * bf2f_hi(v1.w);
        rrc[0] = rrn[0]; rrc[1] = rrn[1];
    }
#undef LOAD_REC

    // combine the 4 edge slots within each 32-lane node group
    #pragma unroll
    for (int i = 0; i < 8; ++i) {
        a[i] += __shfl_xor(a[i], 8);
        a[i] += __shfl_xor(a[i], 16);
    }

    if (valid && slot == 0) {
        float dn = dis[node];
        int c0 = plane * 64 + cl * 8;
        float4 b0 = *(const float4*)(bias + c0);
        float4 b1 = *(const float4*)(bias + c0 + 4);
        f32x4 o0 = {a[0] * dn + b0.x, a[1] * dn + b0.y, a[2] * dn + b0.z, a[3] * dn + b0.w};
        f32x4 o1 = {a[4] * dn + b1.x, a[5] * dn + b1.y, a[6] * dn + b1.z, a[7] * dn + b1.w};
        f32x4* op = (f32x4*)(out + (size_t)node * COUT + c0);
        __builtin_nontemporal_store(o0, op);        // write-once: keep out of L2
        __builtin_nontemporal_store(o1, op + 1);
    }
}

// ---------------- launch ----------------
extern "C" void kernel_launch(void* const* d_in, const int* in_sizes, int n_in,
                              void* d_out, int out_size, void* d_ws, size_t ws_size,
                              hipStream_t stream) {
    const float* X    = (const float*)d_in[0];
    const int*   ei   = (const int*)d_in[1];
    const float* ew   = (const float*)d_in[2];
    const float* W    = (const float*)d_in[3];
    const float* bias = (const float*)d_in[4];
    float* out = (float*)d_out;

    int E = in_sizes[2];            // edge_weight count
    int N = out_size / COUT;        // B == 1
    int NB = (N + 255) >> 8;        // buckets of 256 nodes

    // workspace carve-up (~75 MB)
    char* ws = (char*)d_ws;
    unsigned short*     h    = (unsigned short*)ws;     ws += (size_t)N * COUT * 2;     // 25.6 MB (2 planes)
    unsigned long long* brec = (unsigned long long*)ws; ws += (size_t)NB * BCAP * 8;    // 32.0 MB
    unsigned int*       srec = (unsigned int*)ws;       ws += (size_t)NB * BCAP * 4;    // 16.0 MB
    int2*               rinf = (int2*)ws;               ws += (size_t)N * 8;            // 0.8 MB
    float*              dis  = (float*)ws;              ws += (size_t)(N + 64) * 4;     // +64 pad (gemm f4 reads)
    int*                cur  = (int*)ws;                ws += (size_t)NB * 4;
    unsigned short*     WB   = (unsigned short*)ws;     ws += 8 * 4 * 64 * 8 * 2;       // 32 KB

    k_zero   <<<(NB + 255) / 256, 256, 0, stream>>>(cur, NB);
    k_part   <<<(E + EPB - 1) / EPB, 256, 0, stream>>>(ei, ew, cur, brec, E, NB);
    k_sortdeg<<<NB, 256, 0, stream>>>(brec, cur, srec, rinf, dis, N);
    k_wprep  <<<1, 256, 0, stream>>>(W, WB);
    k_gemm   <<<(N + 63) / 64, 256, 0, stream>>>(X, WB, dis, h, N);
    k_agg    <<<(N + 7) / 8, 256, 0, stream>>>(h, srec, rinf, dis, bias, out, N, 0);
    k_agg    <<<(N + 7) / 8, 256, 0, stream>>>(h, srec, rinf, dis, bias, out, N, 1);
}